// Round 10
// baseline (344.118 us; speedup 1.0000x reference)
//
#include <hip/hip_runtime.h>
#include <hip/hip_bf16.h>

// Self-attention: B=4, S=2048, D=768, fp32 in/out, bf16 MFMA internally.
// R16: fused Es+PV v3 — spill eliminated BY CONSTRUCTION. R15's null showed
// __launch_bounds__ can't lift the 128-VGPR allocation for 512-thr blocks;
// the ~150-live-reg working set spilled 52 MB/dispatch (WRITE 77.3 vs 25.2
// output, constant across (512,2) and (512,1)). v3: 1024 thr / 16 waves —
// per-thread state halves (acc_o 24, sAcc 8, va 12; live ~113 < 128), no
// spill possible. Same algorithm (3x verified), same K-glds16 staging +
// O^T-form PV + swizzled Q/P (R14's FETCH showed line-efficiency). Grid 256
// blocks (1/CU), LDS 128 KiB, MFMA floor ~26 us unchanged.
// QKV stays 128x128 2-phase + XCD swizzle; prep unchanged.
// ws: Xb | WqT WkT WvT | Qb Kb Vt

typedef __attribute__((ext_vector_type(8))) short short8;
typedef __attribute__((ext_vector_type(4))) short short4v;
typedef __attribute__((ext_vector_type(4))) float float4v;

static constexpr int B_ = 4, S_ = 2048, D_ = 768;
static constexpr int MS = B_ * S_;  // 8192

__device__ inline short f2bf(float f) {
  __hip_bfloat16 h = __float2bfloat16(f);
  union { __hip_bfloat16 h; short s; } u; u.h = h; return u.s;
}

typedef const __attribute__((address_space(1))) unsigned int g_u32;
typedef __attribute__((address_space(3))) unsigned int l_u32;

__device__ __forceinline__ void glds16(const short* g, short* l) {
  __builtin_amdgcn_global_load_lds((g_u32*)g, (l_u32*)l, 16, 0, 0);
}

// XCD-chunked bijective remap (valid when (gridDim.x*gridDim.y) % 8 == 0).
__device__ __forceinline__ void xcd_swizzle(int& bx, int& by) {
  const int gx = gridDim.x, nxy = gx * gridDim.y;
  const int oid = blockIdx.y * gx + blockIdx.x;
  const int nid = (oid & 7) * (nxy >> 3) + (oid >> 3);
  bx = nid % gx;
  by = nid / gx;
}

// Fused prep: z=0 -> cast x f32->bf16; z=1 -> transpose+cast the three W.
__global__ __launch_bounds__(256)
void prep(const float* __restrict__ x, short* __restrict__ Xb,
          const float* __restrict__ W0, const float* __restrict__ W1,
          const float* __restrict__ W2,
          short* __restrict__ T0, short* __restrict__ T1, short* __restrict__ T2) {
  __shared__ float tile[32][33];
  const int t = threadIdx.x;
  if (blockIdx.z == 0) {
    int i = (blockIdx.x * 256 + t) * 4;   // grid.x = 6144 covers MS*D_ exactly
    float4v v = *(const float4v*)(x + i);
    short4v o;
    o.x = f2bf(v.x); o.y = f2bf(v.y); o.z = f2bf(v.z); o.w = f2bf(v.w);
    *(short4v*)(Xb + i) = o;
  } else {
    int wid = blockIdx.x;
    if (wid >= 1728) return;              // 24*24*3
    int wz = wid / 576, rem = wid - wz * 576;
    int wy = rem / 24, wx = rem - wy * 24;
    const float* W = wz == 0 ? W0 : (wz == 1 ? W1 : W2);
    short* T = wz == 0 ? T0 : (wz == 1 ? T1 : T2);
    int bx = wx * 32, by = wy * 32;
    int tx = t & 31, ty = t >> 5;
    for (int r = ty; r < 32; r += 8)
      tile[r][tx] = W[(by + r) * D_ + bx + tx];
    __syncthreads();
    for (int r = ty; r < 32; r += 8)
      T[(bx + r) * D_ + by + tx] = f2bf(tile[tx][r]);
  }
}

// ---------------------------------------------------------------------------
// 128x128 2-phase kernel — QKV tri-output only.
// ---------------------------------------------------------------------------
template<int TM, int TN>
__global__ __launch_bounds__(256)
void gemm_bt(const short* __restrict__ A, const short* __restrict__ Bt,
             short* __restrict__ C0, short* __restrict__ C1, short* __restrict__ C2,
             const float* __restrict__ bias0, const float* __restrict__ bias1,
             const float* __restrict__ bias2,
             int K, int lda, int ldb) {
  constexpr int BMv = TM * 32, BNv = TN * 32;

  __shared__ short As[BMv * 64];
  __shared__ short Bs[BNv * 64];

  const int t = threadIdx.x;
  const int wave = t >> 6, lane = t & 63;
  const int lane16 = lane & 15, q = lane >> 4;
  int bxs, bys;
  xcd_swizzle(bxs, bys);
  const int m0 = bys * BMv, n0 = bxs * BNv;
  const int wm = (wave >> 1) * (TM * 16), wn = (wave & 1) * (TN * 16);
  const int rsub = lane >> 3;
  const int g = (lane & 7) ^ rsub;

  auto stage = [&](int kk) {
#pragma unroll
    for (int i = wave; i < BMv / 8; i += 4)
      glds16(A + (long)(m0 + i * 8 + rsub) * lda + kk + g * 8, &As[i * 512]);
#pragma unroll
    for (int i = wave; i < BNv / 8; i += 4)
      glds16(Bt + (long)(n0 + i * 8 + rsub) * ldb + kk + g * 8, &Bs[i * 512]);
  };

  stage(0);

  float4v acc[TM][TN];
#pragma unroll
  for (int i = 0; i < TM; i++)
#pragma unroll
    for (int j = 0; j < TN; j++) acc[i][j] = {0.f, 0.f, 0.f, 0.f};

  for (int k0 = 0; k0 < K; k0 += 64) {
    __syncthreads();  // B1: drains stage(k0) [vmcnt(0)] + wave sync

    short8 af[2][TM], bfr[2][TN];
#pragma unroll
    for (int s = 0; s < 2; s++) {
#pragma unroll
      for (int i = 0; i < TM; i++) {
        int R = wm + i * 16 + lane16;
        af[s][i] = *(const short8*)&As[R * 64 + (((s * 4 + q) ^ (R & 7)) * 8)];
      }
#pragma unroll
      for (int j = 0; j < TN; j++) {
        int R = wn + j * 16 + lane16;
        bfr[s][j] = *(const short8*)&Bs[R * 64 + (((s * 4 + q) ^ (R & 7)) * 8)];
      }
    }
    __syncthreads();  // B2: all waves done reading LDS

    if (k0 + 64 < K) stage(k0 + 64);  // async; overlaps the MFMA pack below

#pragma unroll
    for (int s = 0; s < 2; s++)
#pragma unroll
      for (int i = 0; i < TM; i++)
#pragma unroll
        for (int j = 0; j < TN; j++)
          acc[i][j] = __builtin_amdgcn_mfma_f32_16x16x32_bf16(af[s][i], bfr[s][j], acc[i][j], 0, 0, 0);
  }

#pragma unroll
  for (int i = 0; i < TM; i++) {
    int mrow = m0 + wm + i * 16 + q * 4;
#pragma unroll
    for (int j = 0; j < TN; j++) {
      int ncol = n0 + wn + j * 16 + lane16;   // tile-uniform branch: bounds %16
      if (ncol < 1536) {
        short* dst = ncol < 768 ? C0 : C1;
        const float* bs = ncol < 768 ? bias0 : bias1;
        int c = ncol < 768 ? ncol : ncol - 768;   // NOT `& 767` (768 != pow2)
#pragma unroll
        for (int rr = 0; rr < 4; rr++)
          dst[(long)(mrow + rr) * 768 + c] = f2bf(acc[i][j][rr] + bs[c]);
      } else {
        int e = ncol - 1536;
        float bv = bias2[e];
        short4v o;
#pragma unroll
        for (int rr = 0; rr < 4; rr++) o[rr] = f2bf(acc[i][j][rr] + bv);
        *(short4v*)&C2[(long)e * MS + mrow] = o;   // Vt[e][m], 8-B store
      }
    }
  }
}

// ---------------------------------------------------------------------------
// Fused attention v3 (16 waves, spill-free by construction).
// Block = (batch, 32-q-row tile) = 256 blk, 1024 thr.
// S stage: KVBLK=256, d-loop 12 x BK=64 (K glds16-staged dbuf); wave w owns
// kv cols [w*16, w*16+16): 4 MFMA / d-iter (2 m-frags x 2 s).
// P = exp(S*scale) -> Ps[32][256] bf16, granule-XOR swizzled.
// PV (O^T): A = V (rows e, per-lane contiguous 16B global), B = P (LDS);
// wave w owns e rows [w*48, w*48+48): 6 MFMA / 32-kv chunk.
// Pipeline: d-loop of tile tt interleaves PV chunks of tile tt-1.
// ---------------------------------------------------------------------------
__global__ __launch_bounds__(1024)
void fused_attn3(const short* __restrict__ Qb, const short* __restrict__ Kb,
                 const short* __restrict__ Vt, float* __restrict__ out,
                 float scale) {
  const int x = blockIdx.x;
  const int xcd = x & 7, kblk = x >> 3;
  const int b = xcd >> 1;
  const int q0 = ((kblk << 1) | (xcd & 1)) * 32;

  __shared__ short Qs[12 * 32 * 64];   // 48 KiB: 12 d-chunks x [32 r][64]
  __shared__ short Ks[2][256 * 64];    // 64 KiB: dbuf [256 kv][64]
  __shared__ short Ps[32 * 256];       // 16 KiB: [32 q][256 kv] swizzled

  const int t = threadIdx.x;
  const int wave = t >> 6, lane = t & 63;   // wave 0..15
  const int lane16 = lane & 15, q = lane >> 4;
  const int rsub = lane >> 3;
  const int g = (lane & 7) ^ rsub;

  // ---- stage Q: 12 chunks x 4 rowblocks = 48 glds16, 3 per wave ----
  {
    const short* qsrc = Qb + (long)(b * 2048 + q0) * 768;
#pragma unroll
    for (int i = 0; i < 3; i++) {
      int id = wave + 16 * i;          // 0..47
      int ch = id >> 2, rb = id & 3;
      glds16(qsrc + (long)(rb * 8 + rsub) * 768 + ch * 64 + g * 8,
             &Qs[ch * 2048 + rb * 512]);
    }
  }

  const short* kbb = Kb + (long)(b * 2048) * 768;
  auto stageK = [&](int buf, int kv0, int ch) {
#pragma unroll
    for (int j = 0; j < 2; j++) {
      int i = wave + 16 * j;           // rowblock 0..31
      glds16(kbb + (long)(kv0 + i * 8 + rsub) * 768 + ch * 64 + g * 8,
             &Ks[buf][i * 512]);
    }
  };
  stageK(0, 0, 0);

  float4v acc_o[3][2];
#pragma unroll
  for (int m = 0; m < 3; m++)
#pragma unroll
    for (int n = 0; n < 2; n++) acc_o[m][n] = {0.f, 0.f, 0.f, 0.f};
  float4v acc_rs[2];
  acc_rs[0] = {0.f, 0.f, 0.f, 0.f};
  acc_rs[1] = {0.f, 0.f, 0.f, 0.f};
  short8 ones;
#pragma unroll
  for (int e = 0; e < 8; e++) ones[e] = (short)0x3F80;  // bf16 1.0

  const short* vbb = Vt + (long)b * 2048;

  int cur = 0;
  for (int tt = 0; tt <= 8; ++tt) {
    const int kvp = (tt - 1) * 256;    // PV tile (valid for tt>=1)
    if (tt < 8) {
      const int kv0 = tt * 256;
      float4v sAcc[2];
      sAcc[0] = {0.f, 0.f, 0.f, 0.f};
      sAcc[1] = {0.f, 0.f, 0.f, 0.f};

      for (int ch = 0; ch < 12; ++ch) {
        __syncthreads();               // drains K stage (+Q at tt=0,ch=0)
        short8 a[2][2], bf[2];
#pragma unroll
        for (int m = 0; m < 2; m++) {
          int R = m * 16 + lane16;
#pragma unroll
          for (int s = 0; s < 2; s++)
            a[m][s] = *(const short8*)&Qs[ch * 2048 + R * 64 + (((s * 4 + q) ^ (R & 7)) * 8)];
        }
        {
          int R = wave * 16 + lane16;
#pragma unroll
          for (int s = 0; s < 2; s++)
            bf[s] = *(const short8*)&Ks[cur][R * 64 + (((s * 4 + q) ^ (R & 7)) * 8)];
        }
        __syncthreads();               // buffer free for restage
        if (ch < 11) stageK(cur ^ 1, kv0, ch + 1);
        else if (tt + 1 < 8) stageK(cur ^ 1, kv0 + 256, 0);

        if (tt >= 1 && ch < 8) {
          // PV chunk ch of tile tt-1: issue V loads early, MFMA after S
          short8 va[3], pb[2];
#pragma unroll
          for (int m = 0; m < 3; m++) {
            int e = wave * 48 + m * 16 + lane16;
            va[m] = *(const short8*)&vbb[(long)e * 8192 + kvp + ch * 32 + q * 8];
          }
#pragma unroll
          for (int n = 0; n < 2; n++) {
            int R = n * 16 + lane16;
            pb[n] = *(const short8*)&Ps[R * 256 + (((ch * 4 + q) ^ (R & 7)) * 8)];
          }
#pragma unroll
          for (int s = 0; s < 2; s++)
#pragma unroll
            for (int m = 0; m < 2; m++)
              sAcc[m] = __builtin_amdgcn_mfma_f32_16x16x32_bf16(a[m][s], bf[s], sAcc[m], 0, 0, 0);
          if (wave == 0) {
            acc_rs[0] = __builtin_amdgcn_mfma_f32_16x16x32_bf16(ones, pb[0], acc_rs[0], 0, 0, 0);
            acc_rs[1] = __builtin_amdgcn_mfma_f32_16x16x32_bf16(ones, pb[1], acc_rs[1], 0, 0, 0);
          }
#pragma unroll
          for (int m = 0; m < 3; m++)
#pragma unroll
            for (int n = 0; n < 2; n++)
              acc_o[m][n] = __builtin_amdgcn_mfma_f32_16x16x32_bf16(va[m], pb[n], acc_o[m][n], 0, 0, 0);
        } else {
#pragma unroll
          for (int s = 0; s < 2; s++)
#pragma unroll
            for (int m = 0; m < 2; m++)
              sAcc[m] = __builtin_amdgcn_mfma_f32_16x16x32_bf16(a[m][s], bf[s], sAcc[m], 0, 0, 0);
        }
        cur ^= 1;
      }

      // P(tt) = exp(S*scale) -> Ps (all PV reads of tile tt-1 ended several
      // barriers ago; next readers sync first)
#pragma unroll
      for (int m = 0; m < 2; m++)
#pragma unroll
        for (int rr = 0; rr < 4; rr++) {
          int row = m * 16 + q * 4 + rr;
          int c = wave * 16 + lane16;
          int gr = (c >> 3) ^ (row & 7);
          Ps[row * 256 + gr * 8 + (c & 7)] = f2bf(__expf(sAcc[m][rr] * scale));
        }
    } else {
      // tt == 8: standalone PV of tile 7
      __syncthreads();                 // Ps(7) visible
#pragma unroll
      for (int ch = 0; ch < 8; ++ch) {
        short8 va[3], pb[2];
#pragma unroll
        for (int m = 0; m < 3; m++) {
          int e = wave * 48 + m * 16 + lane16;
          va[m] = *(const short8*)&vbb[(long)e * 8192 + kvp + ch * 32 + q * 8];
        }
#pragma unroll
        for (int n = 0; n < 2; n++) {
          int R = n * 16 + lane16;
          pb[n] = *(const short8*)&Ps[R * 256 + (((ch * 4 + q) ^ (R & 7)) * 8)];
        }
        if (wave == 0) {
          acc_rs[0] = __builtin_amdgcn_mfma_f32_16x16x32_bf16(ones, pb[0], acc_rs[0], 0, 0, 0);
          acc_rs[1] = __builtin_amdgcn_mfma_f32_16x16x32_bf16(ones, pb[1], acc_rs[1], 0, 0, 0);
        }
#pragma unroll
        for (int m = 0; m < 3; m++)
#pragma unroll
          for (int n = 0; n < 2; n++)
            acc_o[m][n] = __builtin_amdgcn_mfma_f32_16x16x32_bf16(va[m], pb[n], acc_o[m][n], 0, 0, 0);
      }
    }
  }

  // ---- rowsums (wave 0) -> reuse Ps as float scratch; divide + store ----
  __syncthreads();                     // PV(7) reads of Ps done everywhere
  float* rsf = (float*)&Ps[0];
  if (wave == 0 && lane < 16) {
    rsf[lane] = acc_rs[0][0];          // q tokens 0..15 (C/D col = lane16)
    rsf[16 + lane] = acc_rs[1][0];     // q tokens 16..31
  }
  __syncthreads();

  float* ob = out + (long)(b * 2048 + q0) * 768;
#pragma unroll
  for (int n = 0; n < 2; n++) {
    int qcol = n * 16 + lane16;
    float inv = 1.0f / rsf[qcol];
#pragma unroll
    for (int m = 0; m < 3; m++) {
      int e0 = wave * 48 + m * 16 + q * 4;
      float4v o;
#pragma unroll
      for (int rr = 0; rr < 4; rr++) o[rr] = acc_o[m][n][rr] * inv;
      *(float4v*)&ob[(long)qcol * 768 + e0] = o;   // 16-B aligned
    }
  }
}

extern "C" void kernel_launch(void* const* d_in, const int* in_sizes, int n_in,
                              void* d_out, int out_size, void* d_ws, size_t ws_size,
                              hipStream_t stream) {
  const float* x  = (const float*)d_in[0];
  const float* Wq = (const float*)d_in[1];
  const float* bq = (const float*)d_in[2];
  const float* Wk = (const float*)d_in[3];
  const float* bk = (const float*)d_in[4];
  const float* Wv = (const float*)d_in[5];
  const float* bv = (const float*)d_in[6];
  float* out = (float*)d_out;

  short* Xb  = (short*)d_ws;                     // [8192][768]
  short* WqT = Xb + (long)MS * D_;               // [2304][768] = WqT||WkT||WvT
  short* WkT = WqT + (long)D_ * D_;
  short* WvT = WkT + (long)D_ * D_;
  short* Qb  = WvT + (long)D_ * D_;              // [8192][768]
  short* Kb  = Qb + (long)MS * D_;               // [8192][768]
  short* Vt  = Kb + (long)MS * D_;               // [768][8192]

  // Fused prep: cast x (z=0) + transpose/cast W (z=1)
  prep<<<dim3(6144, 1, 2), 256, 0, stream>>>(x, Xb, Wq, Wk, Wv, WqT, WkT, WvT);

  // Q||K||Vt = Xb @ [WqT;WkT;WvT]^T + biases  (128x128 2-phase, 18x64 blk)
  gemm_bt<4, 4><<<dim3(2304 / 128, MS / 128, 1), 256, 0, stream>>>(
      Xb, WqT, Qb, Kb, Vt, bq, bk, bv, D_, D_, D_);

  // Fused attention v3: 256 blocks (perfect CU fit), 1024 threads
  fused_attn3<<<dim3(256, 1, 1), 1024, 0, stream>>>(
      Qb, Kb, Vt, out, 1.0f / sqrtf((float)D_));
}

// Round 11
// 193.536 us; speedup vs baseline: 1.7781x; 1.7781x over previous
//
#include <hip/hip_runtime.h>
#include <hip/hip_bf16.h>

// Self-attention: B=4, S=2048, D=768, fp32 in/out, bf16 MFMA internally.
// R17: REVERT to R11 (best measured: 195.88 us), per R16's pre-commitment.
// The fused Es+PV line is dead by resource law: a B-thread block at 1
// block/CU gets a 256*256/B VGPR budget (512->128, 1024->64 — both measured
// via VGPR_Count), so the ~150-reg fused working set spills at any B >= 512,
// and B=256 leaves 1 wave/SIMD under the 128 KiB LDS (no latency hiding).
// Config: QKV 128x128 2-phase + XCD chunk swizzle (FETCH 64->35 MB, R11);
// Es 256x256 8-phase (grid 256 = perfect CU fit, ~1.4 PF); PV flipped
// 2-phase full-K (O^T form, float4 stores, in-loop ones-MFMA rowsum).
// ws: Xb | WqT WkT WvT | Qb Kb Vt | Es

typedef __attribute__((ext_vector_type(8))) short short8;
typedef __attribute__((ext_vector_type(4))) short short4v;
typedef __attribute__((ext_vector_type(4))) float float4v;

static constexpr int B_ = 4, S_ = 2048, D_ = 768;
static constexpr int MS = B_ * S_;  // 8192

__device__ inline short f2bf(float f) {
  __hip_bfloat16 h = __float2bfloat16(f);
  union { __hip_bfloat16 h; short s; } u; u.h = h; return u.s;
}

typedef const __attribute__((address_space(1))) unsigned int g_u32;
typedef __attribute__((address_space(3))) unsigned int l_u32;

__device__ __forceinline__ void glds16(const short* g, short* l) {
  __builtin_amdgcn_global_load_lds((g_u32*)g, (l_u32*)l, 16, 0, 0);
}

// XCD-chunked bijective remap (valid when (gridDim.x*gridDim.y) % 8 == 0):
// original consecutive ids round-robin XCDs; remap so ids on one XCD form a
// contiguous tile chunk (panel reuse lands in that XCD's private L2).
__device__ __forceinline__ void xcd_swizzle(int& bx, int& by) {
  const int gx = gridDim.x, nxy = gx * gridDim.y;
  const int oid = blockIdx.y * gx + blockIdx.x;
  const int nid = (oid & 7) * (nxy >> 3) + (oid >> 3);
  bx = nid % gx;
  by = nid / gx;
}

__global__ __launch_bounds__(256)
void cast_f32_bf16(const float* __restrict__ x, short* __restrict__ y, int n) {
  int i = (blockIdx.x * 256 + threadIdx.x) * 4;
  if (i + 3 < n) {
    float4v v = *(const float4v*)(x + i);
    short4v o;
    o.x = f2bf(v.x); o.y = f2bf(v.y); o.z = f2bf(v.z); o.w = f2bf(v.w);
    *(short4v*)(y + i) = o;
  }
}

// T[e][d] = (bf16) W[d][e], for three 768x768 matrices
__global__ void transpose_cast_w(const float* __restrict__ W0, const float* __restrict__ W1,
                                 const float* __restrict__ W2,
                                 short* __restrict__ T0, short* __restrict__ T1,
                                 short* __restrict__ T2) {
  const float* W = blockIdx.z == 0 ? W0 : (blockIdx.z == 1 ? W1 : W2);
  short* T = blockIdx.z == 0 ? T0 : (blockIdx.z == 1 ? T1 : T2);
  __shared__ float tile[32][33];
  int bx = blockIdx.x * 32, by = blockIdx.y * 32;
  int tx = threadIdx.x, ty = threadIdx.y;
  for (int r = ty; r < 32; r += 8)
    tile[r][tx] = W[(by + r) * D_ + bx + tx];
  __syncthreads();
  for (int r = ty; r < 32; r += 8)
    T[(bx + r) * D_ + by + tx] = f2bf(tile[tx][r]);
}

// ---------------------------------------------------------------------------
// 128x128 2-phase kernel. EPI 0: QKV tri-output. EPI 4: flipped PV —
// C'[e][q] = sum_k Vt[e][k]*Es[q][k]; out[q][e] = C'/rowsum_q, float4 stores.
// ---------------------------------------------------------------------------
template<int EPI, int TM, int TN>
__global__ __launch_bounds__(256)
void gemm_bt(const short* __restrict__ A, const short* __restrict__ Bt,
             void* __restrict__ C0v, short* __restrict__ C1, short* __restrict__ C2,
             const float* __restrict__ bias0, const float* __restrict__ bias1,
             const float* __restrict__ bias2,
             int K, int lda, int ldb, int ldc,
             long sA, long sB, long sC, float scale) {
  constexpr int BMv = TM * 32, BNv = TN * 32;
  const int b = blockIdx.z;
  A += (long)b * sA;
  Bt += (long)b * sB;
  float* Cf = (float*)C0v + (long)b * sC;
  short* Cs = (short*)C0v + (long)b * sC;

  __shared__ short As[BMv * 64];
  __shared__ short Bs[BNv * 64];

  const int t = threadIdx.x;
  const int wave = t >> 6, lane = t & 63;
  const int lane16 = lane & 15, q = lane >> 4;
  int bxs, bys;
  xcd_swizzle(bxs, bys);
  const int m0 = bys * BMv, n0 = bxs * BNv;
  const int wm = (wave >> 1) * (TM * 16), wn = (wave & 1) * (TN * 16);
  const int rsub = lane >> 3;
  const int g = (lane & 7) ^ rsub;

  auto stage = [&](int kk) {
#pragma unroll
    for (int i = wave; i < BMv / 8; i += 4)
      glds16(A + (long)(m0 + i * 8 + rsub) * lda + kk + g * 8, &As[i * 512]);
#pragma unroll
    for (int i = wave; i < BNv / 8; i += 4)
      glds16(Bt + (long)(n0 + i * 8 + rsub) * ldb + kk + g * 8, &Bs[i * 512]);
  };

  stage(0);

  float4v acc[TM][TN];
#pragma unroll
  for (int i = 0; i < TM; i++)
#pragma unroll
    for (int j = 0; j < TN; j++) acc[i][j] = {0.f, 0.f, 0.f, 0.f};

  // rowsum accumulators: EPI 4 uses TN-indexed col-sums (rowsum of Bt rows)
  float4v acc_rs[TN];
#pragma unroll
  for (int i = 0; i < TN; i++) acc_rs[i] = {0.f, 0.f, 0.f, 0.f};
  short8 ones;
#pragma unroll
  for (int e = 0; e < 8; e++) ones[e] = (short)0x3F80;  // bf16 1.0

  for (int k0 = 0; k0 < K; k0 += 64) {
    __syncthreads();  // B1: drains stage(k0) [vmcnt(0)] + wave sync

    short8 af[2][TM], bfr[2][TN];
#pragma unroll
    for (int s = 0; s < 2; s++) {
#pragma unroll
      for (int i = 0; i < TM; i++) {
        int R = wm + i * 16 + lane16;
        af[s][i] = *(const short8*)&As[R * 64 + (((s * 4 + q) ^ (R & 7)) * 8)];
      }
#pragma unroll
      for (int j = 0; j < TN; j++) {
        int R = wn + j * 16 + lane16;
        bfr[s][j] = *(const short8*)&Bs[R * 64 + (((s * 4 + q) ^ (R & 7)) * 8)];
      }
    }
    __syncthreads();  // B2: all waves done reading LDS

    if (k0 + 64 < K) stage(k0 + 64);  // async; overlaps the MFMA pack below

#pragma unroll
    for (int s = 0; s < 2; s++) {
      if (EPI == 4) {  // rowsum of Bt rows (Es rows q): C[m][n] = sum_k B[n][k]
#pragma unroll
        for (int j = 0; j < TN; j++)
          acc_rs[j] = __builtin_amdgcn_mfma_f32_16x16x32_bf16(ones, bfr[s][j], acc_rs[j], 0, 0, 0);
      }
#pragma unroll
      for (int i = 0; i < TM; i++) {
#pragma unroll
        for (int j = 0; j < TN; j++)
          acc[i][j] = __builtin_amdgcn_mfma_f32_16x16x32_bf16(af[s][i], bfr[s][j], acc[i][j], 0, 0, 0);
      }
    }
  }

#pragma unroll
  for (int i = 0; i < TM; i++) {
    int mrow = m0 + wm + i * 16 + q * 4;
    if (EPI == 0) {
#pragma unroll
      for (int j = 0; j < TN; j++) {
        int ncol = n0 + wn + j * 16 + lane16;   // tile-uniform branch: bounds %16
        if (ncol < 1536) {
          short* dst = ncol < 768 ? Cs : C1;
          const float* bs = ncol < 768 ? bias0 : bias1;
          int c = ncol < 768 ? ncol : ncol - 768;   // NOT `& 767` (768 != pow2)
#pragma unroll
          for (int rr = 0; rr < 4; rr++)
            dst[(long)(mrow + rr) * 768 + c] = f2bf(acc[i][j][rr] + bs[c]);
        } else {
          int e = ncol - 1536;
          float bv = bias2[e];
          short4v o;
#pragma unroll
          for (int rr = 0; rr < 4; rr++) o[rr] = f2bf(acc[i][j][rr] + bv);
          *(short4v*)&C2[(long)e * MS + mrow] = o;   // Vt[e][m], 8-B store
        }
      }
    } else {  // EPI == 4: rows = e, cols = q; out[q][e] = val / rowsum_q
#pragma unroll
      for (int j = 0; j < TN; j++) {
        int ncol = n0 + wn + j * 16 + lane16;       // q token
        float inv = 1.0f / acc_rs[j][0];            // rowsum_q (rr-independent)
        float4v o;
#pragma unroll
        for (int rr = 0; rr < 4; rr++) o[rr] = acc[i][j][rr] * inv;
        *(float4v*)&Cf[(long)ncol * ldc + mrow] = o;  // 16-B aligned (mrow%4==0)
      }
    }
  }
}

// ---------------------------------------------------------------------------
// 256x256 8-phase kernel — Es only (grid 8x8x4 = 256 blocks = perfect CU fit).
// 512 thr = 8 waves (2Mx4N), wave tile 128x64, BK=64, LDS 128 KiB dbuf.
// Per K-tile: 4 phases {ds_read subtile | stage 1 half-tile | barrier |
// lgkmcnt(0) | setprio(1) 16 MFMA setprio(0) | barrier}; vmcnt(6) at phase 4.
// ---------------------------------------------------------------------------
template<int EPI>
__global__ __launch_bounds__(512, 2)
void gemm8p(const short* __restrict__ A, const short* __restrict__ Bt,
            void* __restrict__ C0v, short* __restrict__ C1, short* __restrict__ C2,
            const float* __restrict__ bias0, const float* __restrict__ bias1,
            const float* __restrict__ bias2,
            int K, int lda, int ldb, int ldc,
            long sA, long sB, long sC, float scale) {
  const int b = blockIdx.z;
  A += (long)b * sA;
  Bt += (long)b * sB;
  short* Cs = (short*)C0v + (long)b * sC;

  __shared__ short As[2][256 * 64];   // [buf][row][64 shorts = 128 B, swizzled]
  __shared__ short Bs[2][256 * 64];

  const int t = threadIdx.x;
  const int wave = t >> 6, lane = t & 63;
  const int lane16 = lane & 15, q = lane >> 4;
  const int xr = lane16 & 7;            // row&7 for all fragment reads
  int bxs, bys;
  xcd_swizzle(bxs, bys);
  const int m0 = bys * 256, n0 = bxs * 256;
  const int wm = (wave >> 2) * 128, wn = (wave & 3) * 64;
  const int rsub = lane >> 3;           // row within an 8-row / 1 KB wave-instr
  const int g = (lane & 7) ^ rsub;      // swizzled source chunk
  const int nt = K >> 6;

  // A stage-unit u: rows {u*64..u*64+63} U {128+u*64..}, dead after phase 1/3
  auto stageA = [&](int u, int tt) {
    short* dst = &As[tt & 1][0];
    const short* src = A + tt * 64 + g * 8;
#pragma unroll
    for (int r = 0; r < 2; r++) {
      int row0 = u * 64 + r * 128 + wave * 8;
      glds16(src + (long)(m0 + row0 + rsub) * lda, dst + row0 * 64);
    }
  };
  // B stage-unit u: rows {64k+u*32 .. 64k+u*32+31}, dead after phase 1/2
  auto stageB = [&](int u, int tt) {
    short* dst = &Bs[tt & 1][0];
    const short* src = Bt + tt * 64 + g * 8;
#pragma unroll
    for (int r = 0; r < 2; r++) {
      int idx = r * 8 + wave;
      int row0 = (idx >> 2) * 64 + u * 32 + (idx & 3) * 8;
      glds16(src + (long)(n0 + row0 + rsub) * ldb, dst + row0 * 64);
    }
  };

  float4v acc[8][4];
#pragma unroll
  for (int i = 0; i < 8; i++)
#pragma unroll
    for (int j = 0; j < 4; j++) acc[i][j] = {0.f, 0.f, 0.f, 0.f};

  // prologue: tile0 fully, tile1 first 3 units (order = steady-state order)
  stageA(0, 0); stageA(1, 0); stageB(0, 0); stageB(1, 0);
  if (nt > 1) { stageA(0, 1); stageB(0, 1); stageA(1, 1); }
  if (nt > 1) asm volatile("s_waitcnt vmcnt(6)" ::: "memory");
  else        asm volatile("s_waitcnt vmcnt(0)" ::: "memory");
  __builtin_amdgcn_s_barrier();

#pragma unroll 2
  for (int tt = 0; tt < nt; ++tt) {
    const short* Ab = &As[tt & 1][0];
    const short* Bb = &Bs[tt & 1][0];
    short8 a[4][2], b0[2][2], b1[2][2];

    // ---- phase 1: quadrant (mh0, nh0); stage (tt+1).B-u1 into other buf
#pragma unroll
    for (int ii = 0; ii < 4; ii++) {
      int R = wm + ii * 16 + lane16;
#pragma unroll
      for (int s = 0; s < 2; s++)
        a[ii][s] = *(const short8*)&Ab[R * 64 + (((s * 4 + q) ^ xr) * 8)];
    }
#pragma unroll
    for (int jj = 0; jj < 2; jj++) {
      int R = wn + jj * 16 + lane16;
#pragma unroll
      for (int s = 0; s < 2; s++)
        b0[jj][s] = *(const short8*)&Bb[R * 64 + (((s * 4 + q) ^ xr) * 8)];
    }
    if (tt + 1 < nt) stageB(1, tt + 1);
    __builtin_amdgcn_s_barrier();
    asm volatile("s_waitcnt lgkmcnt(0)" ::: "memory");
    __builtin_amdgcn_sched_barrier(0);
    __builtin_amdgcn_s_setprio(1);
#pragma unroll
    for (int s = 0; s < 2; s++)
#pragma unroll
      for (int ii = 0; ii < 4; ii++)
#pragma unroll
        for (int jj = 0; jj < 2; jj++)
          acc[ii][jj] = __builtin_amdgcn_mfma_f32_16x16x32_bf16(a[ii][s], b0[jj][s], acc[ii][jj], 0, 0, 0);
    __builtin_amdgcn_s_setprio(0);
    __builtin_amdgcn_s_barrier();

    // ---- phase 2: quadrant (mh0, nh1); stage (tt+2).A-u0 (dead since ph1)
#pragma unroll
    for (int jj = 0; jj < 2; jj++) {
      int R = wn + 32 + jj * 16 + lane16;
#pragma unroll
      for (int s = 0; s < 2; s++)
        b1[jj][s] = *(const short8*)&Bb[R * 64 + (((s * 4 + q) ^ xr) * 8)];
    }
    if (tt + 2 < nt) stageA(0, tt + 2);
    __builtin_amdgcn_s_barrier();
    asm volatile("s_waitcnt lgkmcnt(0)" ::: "memory");
    __builtin_amdgcn_sched_barrier(0);
    __builtin_amdgcn_s_setprio(1);
#pragma unroll
    for (int s = 0; s < 2; s++)
#pragma unroll
      for (int ii = 0; ii < 4; ii++)
#pragma unroll
        for (int jj = 0; jj < 2; jj++)
          acc[ii][2 + jj] = __builtin_amdgcn_mfma_f32_16x16x32_bf16(a[ii][s], b1[jj][s], acc[ii][2 + jj], 0, 0, 0);
    __builtin_amdgcn_s_setprio(0);
    __builtin_amdgcn_s_barrier();

    // ---- phase 3: quadrant (mh1, nh1); A-u1 reads; stage (tt+2).B-u0
#pragma unroll
    for (int ii = 0; ii < 4; ii++) {
      int R = wm + 64 + ii * 16 + lane16;
#pragma unroll
      for (int s = 0; s < 2; s++)
        a[ii][s] = *(const short8*)&Ab[R * 64 + (((s * 4 + q) ^ xr) * 8)];
    }
    if (tt + 2 < nt) stageB(0, tt + 2);
    __builtin_amdgcn_s_barrier();
    asm volatile("s_waitcnt lgkmcnt(0)" ::: "memory");
    __builtin_amdgcn_sched_barrier(0);
    __builtin_amdgcn_s_setprio(1);
#pragma unroll
    for (int s = 0; s < 2; s++)
#pragma unroll
      for (int ii = 0; ii < 4; ii++)
#pragma unroll
        for (int jj = 0; jj < 2; jj++)
          acc[4 + ii][2 + jj] = __builtin_amdgcn_mfma_f32_16x16x32_bf16(a[ii][s], b1[jj][s], acc[4 + ii][2 + jj], 0, 0, 0);
    __builtin_amdgcn_s_setprio(0);
    __builtin_amdgcn_s_barrier();

    // ---- phase 4: quadrant (mh1, nh0); stage (tt+2).A-u1 (dead since ph3);
    //      counted vmcnt — guarantees tile tt+1 staged, 3 half-tiles in flight
    if (tt + 2 < nt) stageA(1, tt + 2);
    __builtin_amdgcn_s_barrier();
    __builtin_amdgcn_s_setprio(1);
#pragma unroll
    for (int s = 0; s < 2; s++)
#pragma unroll
      for (int ii = 0; ii < 4; ii++)
#pragma unroll
        for (int jj = 0; jj < 2; jj++)
          acc[4 + ii][jj] = __builtin_amdgcn_mfma_f32_16x16x32_bf16(a[ii][s], b0[jj][s], acc[4 + ii][jj], 0, 0, 0);
    __builtin_amdgcn_s_setprio(0);
    if (tt + 2 < nt) asm volatile("s_waitcnt vmcnt(6)" ::: "memory");
    else             asm volatile("s_waitcnt vmcnt(0)" ::: "memory");
    __builtin_amdgcn_s_barrier();
  }

  // epilogue (EPI == 2): bf16 out = exp(acc*scale)
#pragma unroll
  for (int i = 0; i < 8; i++) {
    int mrow = m0 + wm + i * 16 + q * 4;
#pragma unroll
    for (int j = 0; j < 4; j++) {
      int ncol = n0 + wn + j * 16 + lane16;
#pragma unroll
      for (int rr = 0; rr < 4; rr++)
        Cs[(long)(mrow + rr) * ldc + ncol] = f2bf(__expf(acc[i][j][rr] * scale));
    }
  }
}

extern "C" void kernel_launch(void* const* d_in, const int* in_sizes, int n_in,
                              void* d_out, int out_size, void* d_ws, size_t ws_size,
                              hipStream_t stream) {
  const float* x  = (const float*)d_in[0];
  const float* Wq = (const float*)d_in[1];
  const float* bq = (const float*)d_in[2];
  const float* Wk = (const float*)d_in[3];
  const float* bk = (const float*)d_in[4];
  const float* Wv = (const float*)d_in[5];
  const float* bv = (const float*)d_in[6];
  float* out = (float*)d_out;

  short* Xb  = (short*)d_ws;                     // [8192][768]
  short* WqT = Xb + (long)MS * D_;               // [2304][768] = WqT||WkT||WvT
  short* WkT = WqT + (long)D_ * D_;
  short* WvT = WkT + (long)D_ * D_;
  short* Qb  = WvT + (long)D_ * D_;              // [8192][768]
  short* Kb  = Qb + (long)MS * D_;               // [8192][768]
  short* Vt  = Kb + (long)MS * D_;               // [768][8192]
  short* Es  = Vt + (long)MS * D_;               // [4][2048][2048] exp(scores)

  cast_f32_bf16<<<(MS * D_) / 1024, 256, 0, stream>>>(x, Xb, MS * D_);
  transpose_cast_w<<<dim3(24, 24, 3), dim3(32, 8), 0, stream>>>(Wq, Wk, Wv, WqT, WkT, WvT);

  // Q||K||Vt = Xb @ [WqT;WkT;WvT]^T + biases  (128x128 2-phase, 18x64 blk)
  gemm_bt<0, 4, 4><<<dim3(2304 / 128, MS / 128, 1), 256, 0, stream>>>(
      Xb, WqT, Qb, Kb, Vt, bq, bk, bv,
      D_, D_, D_, D_, 0, 0, 0, 1.0f);
  // Es[b,q,k] = exp((Qb[b] @ Kb[b]^T)/sqrt(D)) -> bf16  (8x8x4 = 256 blk, 8-phase)
  gemm8p<2><<<dim3(S_ / 256, S_ / 256, B_), 512, 0, stream>>>(
      Qb, Kb, Es, nullptr, nullptr, nullptr, nullptr, nullptr,
      D_, D_, D_, S_,
      (long)S_ * D_, (long)S_ * D_, (long)S_ * S_, 1.0f / sqrtf((float)D_));
  // O^T-form PV: C'[e][q] = Vt[b] @ Es[b]^T; out[q][e] = C'/rowsum_q
  // A = Vt (lda=8192, batch col-window sA=2048), Bt = Es (ldb=2048, sB=S*S)
  gemm_bt<4, 4, 4><<<dim3(S_ / 128, D_ / 128, B_), 256, 0, stream>>>(
      Vt, Es, out, nullptr, nullptr, nullptr, nullptr, nullptr,
      S_, MS, S_, D_,
      (long)S_, (long)S_ * S_, (long)S_ * D_, 1.0f);
}